// Round 4
// baseline (295.820 us; speedup 1.0000x reference)
//
#include <hip/hip_runtime.h>

typedef unsigned short u16;
typedef unsigned int u32;
typedef __bf16 bf16_t;
typedef __bf16 bf16x8 __attribute__((ext_vector_type(8)));
typedef float f32x4 __attribute__((ext_vector_type(4)));

#define NN 5000
#define NF 512
#define NH 64
#define HEADS 8
#define NCLS 40
#define CAP 128
#define LRELU 0.2f

// ---- dtype probe: adj[0][0]==1.0 always (self-loop). fp32 word0=0x3F800000 (low16==0);
// ---- packed-bf16 word0 has low half 0x3F80 != 0. (R2/R3: fp32 path taken on this HW.)
__device__ __forceinline__ bool adj_is_bf16(const void* adj) {
    return ((*(const u32*)adj) & 0xFFFFu) != 0u;
}
__device__ __forceinline__ u16 rne_bf16(float f) {
    u32 u = __float_as_uint(f);
    u += 0x7FFFu + ((u >> 16) & 1u);
    return (u16)(u >> 16);
}
__device__ __forceinline__ float up_bf16(u16 h) {
    return __uint_as_float((u32)h << 16);
}

// ---------------- C0: canonicalize x and W_h to bf16 ----------------
__global__ __launch_bounds__(256) void cvt_ab(const void* __restrict__ x,
                                              const void* __restrict__ W_h,
                                              const void* __restrict__ adj,
                                              u16* __restrict__ xc, u16* __restrict__ whc) {
    const bool isb = adj_is_bf16(adj);
    const int total = NN * NF + HEADS * NF * NH;   // 2,822,144
    for (int i = blockIdx.x * 256 + threadIdx.x; i < total; i += gridDim.x * 256) {
        const void* src; u16* dst; int off;
        if (i < NN * NF) { src = x; dst = xc; off = i; }
        else             { src = W_h; dst = whc; off = i - NN * NF; }
        dst[off] = isb ? ((const u16*)src)[off] : rne_bf16(((const float*)src)[off]);
    }
}

// ---------------- C1: canonicalize small weights to fp32 ----------------
__global__ __launch_bounds__(256) void cvt_small(const void* a_h, const void* W_o, const void* a_o,
                                                 const void* f1w, const void* f1b,
                                                 const void* f2w, const void* f2b,
                                                 const void* adj,
                                                 float* a_hc, float* W_oc, float* a_oc,
                                                 float* f1wc, float* f1bc, float* f2wc, float* f2bc) {
    const bool isb = adj_is_bf16(adj);
    const int s0 = HEADS * 2 * NH, s1 = HEADS * NH * NH, s2 = 2 * NH,
              s3 = NH * 200, s4 = 200, s5 = 200 * NCLS, s6 = NCLS;
    const int total = s0 + s1 + s2 + s3 + s4 + s5 + s6;   // 54,960
    for (int i = blockIdx.x * 256 + threadIdx.x; i < total; i += gridDim.x * 256) {
        const void* src; float* dst; int off = i;
        if (off < s0) { src = a_h; dst = a_hc; }
        else if ((off -= s0) < s1) { src = W_o;  dst = W_oc; }
        else if ((off -= s1) < s2) { src = a_o;  dst = a_oc; }
        else if ((off -= s2) < s3) { src = f1w;  dst = f1wc; }
        else if ((off -= s3) < s4) { src = f1b;  dst = f1bc; }
        else if ((off -= s4) < s5) { src = f2w;  dst = f2wc; }
        else { off -= s5;           src = f2b;  dst = f2bc; }
        dst[off] = isb ? up_bf16(((const u16*)src)[off]) : ((const float*)src)[off];
    }
}

// ---------------- K0: build neighbor lists from dense adjacency (dual dtype) ----------------
__global__ __launch_bounds__(256) void build_csr(const void* __restrict__ adj,
                                                 int* __restrict__ nbr,
                                                 int* __restrict__ deg) {
    const int n = blockIdx.x;
    const bool isb = adj_is_bf16(adj);
    __shared__ int cnt;
    if (threadIdx.x == 0) cnt = 0;
    __syncthreads();
    int* nrow = nbr + (size_t)n * CAP;
    if (isb) {
        const uint4* row4 = (const uint4*)((const u16*)adj + (size_t)n * NN);
        for (int c = threadIdx.x; c < NN / 8; c += 256) {
            uint4 v = row4[c];
            u32 w[4] = {v.x, v.y, v.z, v.w};
            int base = c * 8;
            #pragma unroll
            for (int q = 0; q < 4; ++q) {
                if (w[q] & 0xFFFFu) { int p = atomicAdd(&cnt, 1); if (p < CAP) nrow[p] = base + 2 * q; }
                if (w[q] >> 16)     { int p = atomicAdd(&cnt, 1); if (p < CAP) nrow[p] = base + 2 * q + 1; }
            }
        }
    } else {
        const uint4* row4 = (const uint4*)((const float*)adj + (size_t)n * NN);
        for (int c = threadIdx.x; c < NN / 4; c += 256) {
            uint4 v = row4[c];
            u32 w[4] = {v.x, v.y, v.z, v.w};
            int base = c * 4;
            #pragma unroll
            for (int q = 0; q < 4; ++q)
                if (w[q]) { int p = atomicAdd(&cnt, 1); if (p < CAP) nrow[p] = base + q; }
        }
    }
    __syncthreads();
    if (threadIdx.x == 0) deg[n] = cnt < CAP ? cnt : CAP;
}

// ---------------- K1: Wh[h,n,o] = x @ W_h[h]  (bf16 MFMA, fp32 accum) ----------------
// C/D mapping row=(lane>>4)*4+r, col=lane&15 — confirmed by R3's runtime probe (flag=1).
__global__ __launch_bounds__(256) void gemm1_mfma(const bf16_t* __restrict__ x,
                                                  const bf16_t* __restrict__ W_h,
                                                  float* __restrict__ Wh) {
    const int lane = threadIdx.x & 63;
    const int wid  = threadIdx.x >> 6;
    const int rg = blockIdx.x;   // 0..19
    const int ct = blockIdx.y;   // 0..3
    const int h  = blockIdx.z;   // 0..7
    const int quad = lane >> 4;
    const int lr   = lane & 15;
    const int kq   = quad * 8;
    const int nCol = ct * 16 + lr;
    const bf16_t* Bh = W_h + (size_t)h * NF * NH;

    bf16x8 bfrag[16];
    #pragma unroll
    for (int s = 0; s < 16; ++s) {
        bf16x8 b;
        #pragma unroll
        for (int j = 0; j < 8; ++j) b[j] = Bh[(s * 32 + kq + j) * NH + nCol];
        bfrag[s] = b;
    }

    for (int rt = rg * 4 + wid; rt < (NN + 15) / 16; rt += 80) {
        int row  = rt * 16 + lr;
        int rowc = row < NN ? row : NN - 1;
        const bf16_t* xp = x + (size_t)rowc * NF + kq;
        f32x4 acc = {0.f, 0.f, 0.f, 0.f};
        #pragma unroll
        for (int s = 0; s < 16; ++s) {
            bf16x8 a = *(const bf16x8*)(xp + s * 32);
            acc = __builtin_amdgcn_mfma_f32_16x16x32_bf16(a, bfrag[s], acc, 0, 0, 0);
        }
        #pragma unroll
        for (int r = 0; r < 4; ++r) {
            int gr = rt * 16 + quad * 4 + r;
            if (gr < NN) Wh[((size_t)(h * NN + gr)) * NH + ct * 16 + lr] = acc[r];
        }
    }
}

// ---------------- K2: f1/f2 attention coefficients (wave per (h,n)) ----------------
__global__ __launch_bounds__(256) void attn_coef(const float* __restrict__ Wh,
                                                 const float* __restrict__ a_h,
                                                 float* __restrict__ f1,
                                                 float* __restrict__ f2) {
    const int lane = threadIdx.x & 63;
    const int gw = blockIdx.x * 4 + (threadIdx.x >> 6);   // h*NN + n, exact 40000
    const int h = gw / NN;
    float w  = Wh[(size_t)gw * NH + lane];
    float p1 = w * a_h[h * 128 + lane];
    float p2 = w * a_h[h * 128 + NH + lane];
    #pragma unroll
    for (int o = 32; o; o >>= 1) { p1 += __shfl_xor(p1, o); p2 += __shfl_xor(p2, o); }
    if (lane == 0) { f1[gw] = p1; f2[gw] = p2; }
}

// ---------------- K3: layer-1 sparse softmax + aggregation + ELU + concat ----------------
__global__ __launch_bounds__(256) void agg1(const float* __restrict__ Wh,
                                            const float* __restrict__ f1,
                                            const float* __restrict__ f2,
                                            const int* __restrict__ nbr,
                                            const int* __restrict__ deg,
                                            float* __restrict__ h1) {
    const int lane = threadIdx.x & 63;
    const int wid  = threadIdx.x >> 6;
    const int gw = blockIdx.x * 4 + wid;    // h*NN + n
    const int h = gw / NN;
    const int n = gw - h * NN;
    __shared__ float s_alpha[4][CAP];
    __shared__ int   s_nbr[4][CAP];
    const int d = deg[n];
    const int* nb = nbr + (size_t)n * CAP;
    const float f1n = f1[gw];
    const float* f2h = f2 + (size_t)h * NN;

    float mx = -INFINITY;
    for (int j = lane; j < d; j += 64) {
        int m = nb[j];
        s_nbr[wid][j] = m;
        float e = f1n + f2h[m];
        e = e > 0.f ? e : LRELU * e;
        s_alpha[wid][j] = e;
        mx = fmaxf(mx, e);
    }
    #pragma unroll
    for (int o = 32; o; o >>= 1) mx = fmaxf(mx, __shfl_xor(mx, o));
    float sm = 0.f;
    for (int j = lane; j < d; j += 64) {
        float p = expf(s_alpha[wid][j] - mx);
        s_alpha[wid][j] = p;
        sm += p;
    }
    #pragma unroll
    for (int o = 32; o; o >>= 1) sm += __shfl_xor(sm, o);
    __syncthreads();

    float acc = 0.f;
    const float* WhH = Wh + (size_t)h * NN * NH;
    for (int j = 0; j < d; ++j)
        acc += s_alpha[wid][j] * WhH[(size_t)s_nbr[wid][j] * NH + lane];
    float hv = acc / sm;
    hv = hv > 0.f ? hv : expf(hv) - 1.f;                    // ELU
    h1[(size_t)n * (HEADS * NH) + h * NH + lane] = hv;      // concat heads
}

// ---------------- K4: Wh2 = h1 @ W_o (fp32) + g1/g2 (wave per node) ----------------
__global__ __launch_bounds__(256) void gemm2(const float* __restrict__ h1,
                                             const float* __restrict__ W_o,
                                             const float* __restrict__ a_o,
                                             float* __restrict__ Wh2,
                                             float* __restrict__ g1,
                                             float* __restrict__ g2) {
    const int lane = threadIdx.x & 63;
    const int wid  = threadIdx.x >> 6;
    const int n = blockIdx.x * 4 + wid;    // exact 5000
    __shared__ float sh[4][HEADS * NH];
    const float4* hr = (const float4*)(h1 + (size_t)n * (HEADS * NH));
    ((float4*)sh[wid])[lane]      = hr[lane];
    ((float4*)sh[wid])[lane + 64] = hr[lane + 64];
    __syncthreads();
    float acc = 0.f;
    #pragma unroll 8
    for (int f = 0; f < HEADS * NH; ++f)
        acc += sh[wid][f] * W_o[f * NH + lane];
    Wh2[(size_t)n * NH + lane] = acc;
    float p1 = acc * a_o[lane];
    float p2 = acc * a_o[NH + lane];
    #pragma unroll
    for (int o = 32; o; o >>= 1) { p1 += __shfl_xor(p1, o); p2 += __shfl_xor(p2, o); }
    if (lane == 0) { g1[n] = p1; g2[n] = p2; }
}

// ---------------- K5: layer-2 attention + aggregation + MLP head (wave per node) ----------------
__global__ __launch_bounds__(256) void agg2_mlp(const float* __restrict__ Wh2,
                                                const float* __restrict__ g1,
                                                const float* __restrict__ g2,
                                                const int* __restrict__ nbr,
                                                const int* __restrict__ deg,
                                                const float* __restrict__ fc1_w,
                                                const float* __restrict__ fc1_b,
                                                const float* __restrict__ fc2_w,
                                                const float* __restrict__ fc2_b,
                                                float* __restrict__ out) {
    const int lane = threadIdx.x & 63;
    const int wid  = threadIdx.x >> 6;
    const int n = blockIdx.x * 4 + wid;    // exact 5000
    __shared__ float s_alpha[4][CAP];
    __shared__ int   s_nbr[4][CAP];
    __shared__ float s_h2[4][NH];
    __shared__ float s_h3[4][200];
    const int d = deg[n];
    const int* nb = nbr + (size_t)n * CAP;
    const float gn = g1[n];

    float mx = -INFINITY;
    for (int j = lane; j < d; j += 64) {
        int m = nb[j];
        s_nbr[wid][j] = m;
        float e = gn + g2[m];
        e = e > 0.f ? e : LRELU * e;
        s_alpha[wid][j] = e;
        mx = fmaxf(mx, e);
    }
    #pragma unroll
    for (int o = 32; o; o >>= 1) mx = fmaxf(mx, __shfl_xor(mx, o));
    float sm = 0.f;
    for (int j = lane; j < d; j += 64) {
        float p = expf(s_alpha[wid][j] - mx);
        s_alpha[wid][j] = p;
        sm += p;
    }
    #pragma unroll
    for (int o = 32; o; o >>= 1) sm += __shfl_xor(sm, o);
    __syncthreads();

    float acc = 0.f;
    for (int j = 0; j < d; ++j)
        acc += s_alpha[wid][j] * Wh2[(size_t)s_nbr[wid][j] * NH + lane];
    s_h2[wid][lane] = acc / sm;
    __syncthreads();

    for (int o = lane; o < 200; o += 64) {
        float a = fc1_b[o];
        #pragma unroll 8
        for (int f = 0; f < NH; ++f) a += s_h2[wid][f] * fc1_w[f * 200 + o];
        s_h3[wid][o] = a > 0.f ? a : expf(a) - 1.f;         // ELU
    }
    __syncthreads();

    if (lane < NCLS) {
        float a = fc2_b[lane];
        #pragma unroll 8
        for (int f = 0; f < 200; ++f) a += s_h3[wid][f] * fc2_w[f * NCLS + lane];
        out[(size_t)n * NCLS + lane] = a;                   // fp32 output (reference dtype)
    }
}

extern "C" void kernel_launch(void* const* d_in, const int* in_sizes, int n_in,
                              void* d_out, int out_size, void* d_ws, size_t ws_size,
                              hipStream_t stream) {
    const void* x     = d_in[0];
    const void* adj   = d_in[1];
    const void* W_h   = d_in[2];
    const void* a_h   = d_in[3];
    const void* W_o   = d_in[4];
    const void* a_o   = d_in[5];
    const void* fc1_w = d_in[6];
    const void* fc1_b = d_in[7];
    const void* fc2_w = d_in[8];
    const void* fc2_b = d_in[9];
    float* out = (float*)d_out;

    char* ws = (char*)d_ws;                         // all offsets 16B-aligned
    int*   nbr   = (int*)(ws + 0);                  //  2,560,000 B
    int*   deg   = (int*)(ws + 2560000);            //     20,000 B
    float* Wh    = (float*)(ws + 2580000);          // 10,240,000 B
    float* f1    = (float*)(ws + 12820000);         //    160,000 B
    float* f2    = (float*)(ws + 12980000);         //    160,000 B
    float* h1    = (float*)(ws + 13140000);         // 10,240,000 B
    float* Wh2   = (float*)(ws + 23380000);         //  1,280,000 B
    float* g1    = (float*)(ws + 24660000);         //     20,000 B
    float* g2    = (float*)(ws + 24680000);         //     20,000 B
    u16*   xc    = (u16*)(ws + 24700000);           //  5,120,000 B
    u16*   whc   = (u16*)(ws + 29820000);           //    524,288 B
    float* a_hc  = (float*)(ws + 30344288);         //      4,096 B
    float* W_oc  = (float*)(ws + 30348384);         //    131,072 B
    float* a_oc  = (float*)(ws + 30479456);         //        512 B
    float* f1wc  = (float*)(ws + 30479968);         //     51,200 B
    float* f1bc  = (float*)(ws + 30531168);         //        800 B
    float* f2wc  = (float*)(ws + 30531968);         //     32,000 B
    float* f2bc  = (float*)(ws + 30563968);         //        160 B  (total ~30.6 MB)

    cvt_ab<<<2048, 256, 0, stream>>>(x, W_h, adj, xc, whc);
    cvt_small<<<64, 256, 0, stream>>>(a_h, W_o, a_o, fc1_w, fc1_b, fc2_w, fc2_b, adj,
                                      a_hc, W_oc, a_oc, f1wc, f1bc, f2wc, f2bc);
    build_csr<<<NN, 256, 0, stream>>>(adj, nbr, deg);
    gemm1_mfma<<<dim3(20, 4, HEADS), 256, 0, stream>>>((const bf16_t*)xc, (const bf16_t*)whc, Wh);
    attn_coef<<<HEADS * NN / 4, 256, 0, stream>>>(Wh, a_hc, f1, f2);
    agg1<<<HEADS * NN / 4, 256, 0, stream>>>(Wh, f1, f2, nbr, deg, h1);
    gemm2<<<NN / 4, 256, 0, stream>>>(h1, W_oc, a_oc, Wh2, g1, g2);
    agg2_mlp<<<NN / 4, 256, 0, stream>>>(Wh2, g1, g2, nbr, deg,
                                         f1wc, f1bc, f2wc, f2bc, out);
}

// Round 5
// 281.894 us; speedup vs baseline: 1.0494x; 1.0494x over previous
//
#include <hip/hip_runtime.h>

typedef unsigned short u16;
typedef unsigned int u32;
typedef __bf16 bf16_t;
typedef __bf16 bf16x8 __attribute__((ext_vector_type(8)));
typedef float f32x4 __attribute__((ext_vector_type(4)));

#define NN 5000
#define NF 512
#define NH 64
#define HEADS 8
#define NCLS 40
#define CAP 128
#define LRELU 0.2f

// ---- dtype probe: adj[0][0]==1.0 always (self-loop). fp32 word0=0x3F800000 (low16==0);
// ---- packed-bf16 word0 low half = 0x3F80 != 0. (R2-R4: fp32 path taken on this harness.)
__device__ __forceinline__ bool adj_is_bf16(const void* adj) {
    return ((*(const u32*)adj) & 0xFFFFu) != 0u;
}
__device__ __forceinline__ u16 rne_bf16(float f) {
    u32 u = __float_as_uint(f);
    u += 0x7FFFu + ((u >> 16) & 1u);
    return (u16)(u >> 16);
}
__device__ __forceinline__ float up_bf16(u16 h) {
    return __uint_as_float((u32)h << 16);
}

// ---------------- K0 prep: build CSR + canonicalize inputs (fused; block-uniform roles) ------
#define CVT_AB_BLKS 344
__global__ __launch_bounds__(256) void prep(const void* __restrict__ x, const void* __restrict__ W_h,
                                            const void* __restrict__ adj,
                                            const void* a_h, const void* W_o, const void* a_o,
                                            const void* f1w, const void* f1b,
                                            const void* f2w, const void* f2b,
                                            u16* __restrict__ xc, u16* __restrict__ whc,
                                            float* a_hc, float* W_oc, float* a_oc,
                                            float* f1wc, float* f1bc, float* f2wc, float* f2bc,
                                            int* __restrict__ nbr, int* __restrict__ deg) {
    const bool isb = adj_is_bf16(adj);
    const int b = blockIdx.x;
    if (b < NN) {                       // ---- CSR row b (100 MB HBM scan, the floor) ----
        __shared__ int cnt;
        if (threadIdx.x == 0) cnt = 0;
        __syncthreads();
        int* nrow = nbr + (size_t)b * CAP;
        if (isb) {
            const uint4* row4 = (const uint4*)((const u16*)adj + (size_t)b * NN);
            for (int c = threadIdx.x; c < NN / 8; c += 256) {
                uint4 v = row4[c];
                u32 w[4] = {v.x, v.y, v.z, v.w};
                int base = c * 8;
                #pragma unroll
                for (int q = 0; q < 4; ++q) {
                    if (w[q] & 0xFFFFu) { int p = atomicAdd(&cnt, 1); if (p < CAP) nrow[p] = base + 2 * q; }
                    if (w[q] >> 16)     { int p = atomicAdd(&cnt, 1); if (p < CAP) nrow[p] = base + 2 * q + 1; }
                }
            }
        } else {
            const uint4* row4 = (const uint4*)((const float*)adj + (size_t)b * NN);
            for (int c = threadIdx.x; c < NN / 4; c += 256) {
                uint4 v = row4[c];
                u32 w[4] = {v.x, v.y, v.z, v.w};
                int base = c * 4;
                #pragma unroll
                for (int q = 0; q < 4; ++q)
                    if (w[q]) { int p = atomicAdd(&cnt, 1); if (p < CAP) nrow[p] = base + q; }
            }
        }
        __syncthreads();
        if (threadIdx.x == 0) deg[b] = cnt < CAP ? cnt : CAP;
    } else if (b < NN + CVT_AB_BLKS) {  // ---- x, W_h -> bf16 ----
        const int total = NN * NF + HEADS * NF * NH;   // 2,822,144
        for (int i = (b - NN) * 256 + threadIdx.x; i < total; i += CVT_AB_BLKS * 256) {
            const void* src; u16* dst; int off;
            if (i < NN * NF) { src = x; dst = xc; off = i; }
            else             { src = W_h; dst = whc; off = i - NN * NF; }
            dst[off] = isb ? ((const u16*)src)[off] : rne_bf16(((const float*)src)[off]);
        }
    } else {                            // ---- small weights -> fp32 (8 blocks) ----
        const int s0 = HEADS * 2 * NH, s1 = HEADS * NH * NH, s2 = 2 * NH,
                  s3 = NH * 200, s4 = 200, s5 = 200 * NCLS, s6 = NCLS;
        const int total = s0 + s1 + s2 + s3 + s4 + s5 + s6;   // 54,960
        for (int i = (b - NN - CVT_AB_BLKS) * 256 + threadIdx.x; i < total; i += 8 * 256) {
            const void* src; float* dst; int off = i;
            if (off < s0) { src = a_h; dst = a_hc; }
            else if ((off -= s0) < s1) { src = W_o;  dst = W_oc; }
            else if ((off -= s1) < s2) { src = a_o;  dst = a_oc; }
            else if ((off -= s2) < s3) { src = f1w;  dst = f1wc; }
            else if ((off -= s3) < s4) { src = f1b;  dst = f1bc; }
            else if ((off -= s4) < s5) { src = f2w;  dst = f2wc; }
            else { off -= s5;           src = f2b;  dst = f2bc; }
            dst[off] = isb ? up_bf16(((const u16*)src)[off]) : ((const float*)src)[off];
        }
    }
}

// ---------------- K1: Wh = x @ W_h (bf16 MFMA) + fused f1/f2 epilogue ----------------
// C/D mapping row=(lane>>4)*4+r, col=lane&15 (R3 runtime probe: flag=1). Block = 64 rows x
// all 64 cols of one head; wave wid owns 16-col slice; f1/f2 partials shuffle-reduced over
// the 16-lane col group, summed across waves in LDS.
__global__ __launch_bounds__(256) void gemm1_f(const bf16_t* __restrict__ x,
                                               const bf16_t* __restrict__ W_h,
                                               const float* __restrict__ a_h,
                                               float* __restrict__ Wh,
                                               float* __restrict__ f1,
                                               float* __restrict__ f2) {
    const int lane = threadIdx.x & 63;
    const int wid  = threadIdx.x >> 6;    // 16-col tile
    const int rg = blockIdx.x;            // 0..78 (79*64 = 5056 rows, guarded)
    const int h  = blockIdx.y;
    const int quad = lane >> 4;
    const int lr   = lane & 15;
    const int kq   = quad * 8;
    const int nCol = wid * 16 + lr;
    const bf16_t* Bh = W_h + (size_t)h * NF * NH;
    __shared__ float f1s[4][64], f2s[4][64];

    bf16x8 bfrag[16];
    #pragma unroll
    for (int s = 0; s < 16; ++s) {
        bf16x8 bb;
        #pragma unroll
        for (int j = 0; j < 8; ++j) bb[j] = Bh[(s * 32 + kq + j) * NH + nCol];
        bfrag[s] = bb;
    }
    const float a1c = a_h[h * 128 + nCol];
    const float a2c = a_h[h * 128 + NH + nCol];

    for (int t = 0; t < 4; ++t) {
        const int rb = rg * 64 + t * 16;
        int row  = rb + lr;
        int rowc = row < NN ? row : NN - 1;
        const bf16_t* xp = x + (size_t)rowc * NF + kq;
        f32x4 acc = {0.f, 0.f, 0.f, 0.f};
        #pragma unroll
        for (int s = 0; s < 16; ++s) {
            bf16x8 a = *(const bf16x8*)(xp + s * 32);
            acc = __builtin_amdgcn_mfma_f32_16x16x32_bf16(a, bfrag[s], acc, 0, 0, 0);
        }
        #pragma unroll
        for (int r = 0; r < 4; ++r) {
            int gr = rb + quad * 4 + r;
            if (gr < NN) Wh[((size_t)(h * NN + gr)) * NH + nCol] = acc[r];
            float p1 = acc[r] * a1c, p2 = acc[r] * a2c;
            #pragma unroll
            for (int o = 8; o; o >>= 1) { p1 += __shfl_xor(p1, o); p2 += __shfl_xor(p2, o); }
            if (lr == 0) { f1s[wid][t * 16 + quad * 4 + r] = p1; f2s[wid][t * 16 + quad * 4 + r] = p2; }
        }
    }
    __syncthreads();
    if (wid == 0) {
        int gr = rg * 64 + lane;
        if (gr < NN) {
            f1[h * NN + gr] = f1s[0][lane] + f1s[1][lane] + f1s[2][lane] + f1s[3][lane];
            f2[h * NN + gr] = f2s[0][lane] + f2s[1][lane] + f2s[2][lane] + f2s[3][lane];
        }
    }
}

// ---------------- K2: layer-1 sparse softmax + aggregation + ELU + concat ----------------
// head-major dispatch: concurrent blocks sweep one 1.28MB Wh head-slab (fits per-XCD L2).
__global__ __launch_bounds__(256) void agg1(const float* __restrict__ Wh,
                                            const float* __restrict__ f1,
                                            const float* __restrict__ f2,
                                            const int* __restrict__ nbr,
                                            const int* __restrict__ deg,
                                            float* __restrict__ h1) {
    const int lane = threadIdx.x & 63;
    const int wid  = threadIdx.x >> 6;
    const int gw = blockIdx.x * 4 + wid;    // h*NN + n
    const int h = gw / NN;
    const int n = gw - h * NN;
    __shared__ float s_alpha[4][CAP];       // wave-private slices: no cross-wave barrier needed
    __shared__ int   s_nbr[4][CAP];
    const int d = deg[n];
    const int* nb = nbr + (size_t)n * CAP;
    const float f1n = f1[gw];
    const float* f2h = f2 + (size_t)h * NN;

    float mx = -INFINITY;
    for (int j = lane; j < d; j += 64) {
        int m = nb[j];
        s_nbr[wid][j] = m;
        float e = f1n + f2h[m];
        e = e > 0.f ? e : LRELU * e;
        s_alpha[wid][j] = e;
        mx = fmaxf(mx, e);
    }
    #pragma unroll
    for (int o = 32; o; o >>= 1) mx = fmaxf(mx, __shfl_xor(mx, o));
    float sm = 0.f;
    for (int j = lane; j < d; j += 64) {
        float p = expf(s_alpha[wid][j] - mx);
        s_alpha[wid][j] = p;
        sm += p;
    }
    #pragma unroll
    for (int o = 32; o; o >>= 1) sm += __shfl_xor(sm, o);

    float acc0 = 0.f, acc1 = 0.f;
    const float* WhL = Wh + (size_t)h * NN * NH + lane;
    int j = 0;
    for (; j + 2 <= d; j += 2) {
        acc0 += s_alpha[wid][j]     * WhL[(size_t)s_nbr[wid][j]     * NH];
        acc1 += s_alpha[wid][j + 1] * WhL[(size_t)s_nbr[wid][j + 1] * NH];
    }
    if (j < d) acc0 += s_alpha[wid][j] * WhL[(size_t)s_nbr[wid][j] * NH];
    float hv = (acc0 + acc1) / sm;
    hv = hv > 0.f ? hv : expf(hv) - 1.f;                    // ELU
    h1[(size_t)n * (HEADS * NH) + h * NH + lane] = hv;      // concat heads
}

// ---------------- K3: Wh2 = h1 @ W_o + g1/g2 — 4 nodes/block, W_o read once/block --------
__global__ __launch_bounds__(256) void gemm2_4(const float* __restrict__ h1,
                                               const float* __restrict__ W_o,
                                               const float* __restrict__ a_o,
                                               float* __restrict__ Wh2,
                                               float* __restrict__ g1,
                                               float* __restrict__ g2) {
    const int t = threadIdx.x;
    const int n0 = blockIdx.x * 4;          // exact 5000
    __shared__ float sh[4 * 512];           // 4 nodes' h1
    __shared__ float ps[4][4][64];          // (k-part, node, o)
    const float4* src = (const float4*)(h1 + (size_t)n0 * 512);
    ((float4*)sh)[t]       = src[t];
    ((float4*)sh)[t + 256] = src[t + 256];
    __syncthreads();
    const int o = t & 63, part = t >> 6;    // each thread: one o, one 128-wide k-slice, 4 nodes
    float a0 = 0.f, a1 = 0.f, a2 = 0.f, a3 = 0.f;
    const float* wo = W_o + part * 128 * 64 + o;
    const float* s0 = sh + part * 128;
    #pragma unroll 4
    for (int f = 0; f < 128; ++f) {
        float w = wo[f * 64];               // loaded once, used 4x
        a0 += s0[f] * w; a1 += s0[512 + f] * w; a2 += s0[1024 + f] * w; a3 += s0[1536 + f] * w;
    }
    ps[part][0][o] = a0; ps[part][1][o] = a1; ps[part][2][o] = a2; ps[part][3][o] = a3;
    __syncthreads();
    const int nd = t >> 6;                  // wave = node; lane = o
    float w2 = ps[0][nd][o] + ps[1][nd][o] + ps[2][nd][o] + ps[3][nd][o];
    Wh2[(size_t)(n0 + nd) * 64 + o] = w2;
    float p1 = w2 * a_o[o], p2 = w2 * a_o[64 + o];
    #pragma unroll
    for (int s = 32; s; s >>= 1) { p1 += __shfl_xor(p1, s); p2 += __shfl_xor(p2, s); }
    if (o == 0) { g1[n0 + nd] = p1; g2[n0 + nd] = p2; }
}

// ---------------- K4: layer-2 attention + aggregation + MLP head ----------------
__global__ __launch_bounds__(256) void agg2_mlp(const float* __restrict__ Wh2,
                                                const float* __restrict__ g1,
                                                const float* __restrict__ g2,
                                                const int* __restrict__ nbr,
                                                const int* __restrict__ deg,
                                                const float* __restrict__ fc1_w,
                                                const float* __restrict__ fc1_b,
                                                const float* __restrict__ fc2_w,
                                                const float* __restrict__ fc2_b,
                                                float* __restrict__ out) {
    const int lane = threadIdx.x & 63;
    const int wid  = threadIdx.x >> 6;
    const int t = threadIdx.x;
    const int n0 = blockIdx.x * 4;          // exact 5000
    const int n = n0 + wid;                 // gather phase: wave = node
    __shared__ float s_alpha[4][CAP];
    __shared__ int   s_nbr[4][CAP];
    __shared__ float s_h2[4][NH];
    __shared__ float s_h3[4][200];
    __shared__ float ps2[2][4][NCLS];
    const int d = deg[n];
    const int* nb = nbr + (size_t)n * CAP;
    const float gn = g1[n];

    float mx = -INFINITY;
    for (int j = lane; j < d; j += 64) {
        int m = nb[j];
        s_nbr[wid][j] = m;
        float e = gn + g2[m];
        e = e > 0.f ? e : LRELU * e;
        s_alpha[wid][j] = e;
        mx = fmaxf(mx, e);
    }
    #pragma unroll
    for (int o = 32; o; o >>= 1) mx = fmaxf(mx, __shfl_xor(mx, o));
    float sm = 0.f;
    for (int j = lane; j < d; j += 64) {
        float p = expf(s_alpha[wid][j] - mx);
        s_alpha[wid][j] = p;
        sm += p;
    }
    #pragma unroll
    for (int o = 32; o; o >>= 1) sm += __shfl_xor(sm, o);

    float acc0 = 0.f, acc1 = 0.f;
    int j = 0;
    for (; j + 2 <= d; j += 2) {
        acc0 += s_alpha[wid][j]     * Wh2[(size_t)s_nbr[wid][j]     * NH + lane];
        acc1 += s_alpha[wid][j + 1] * Wh2[(size_t)s_nbr[wid][j + 1] * NH + lane];
    }
    if (j < d) acc0 += s_alpha[wid][j] * Wh2[(size_t)s_nbr[wid][j] * NH + lane];
    s_h2[wid][lane] = (acc0 + acc1) / sm;
    __syncthreads();

    // fc1: 200 threads x 4 nodes, fc1_w read once/block
    if (t < 200) {
        float b0 = 0.f, b1 = 0.f, b2 = 0.f, b3 = 0.f;
        #pragma unroll 4
        for (int f = 0; f < NH; ++f) {
            float w = fc1_w[f * 200 + t];
            b0 += s_h2[0][f] * w; b1 += s_h2[1][f] * w; b2 += s_h2[2][f] * w; b3 += s_h2[3][f] * w;
        }
        float bb = fc1_b[t];
        b0 += bb; b1 += bb; b2 += bb; b3 += bb;
        s_h3[0][t] = b0 > 0.f ? b0 : expf(b0) - 1.f;
        s_h3[1][t] = b1 > 0.f ? b1 : expf(b1) - 1.f;
        s_h3[2][t] = b2 > 0.f ? b2 : expf(b2) - 1.f;
        s_h3[3][t] = b3 > 0.f ? b3 : expf(b3) - 1.f;
    }
    __syncthreads();

    // fc2: 80 threads = (f-half, class) x 4 nodes; fc2_w read 2x/block
    if (t < 80) {
        const int o = t % 40, fh = t / 40;
        float c0 = 0.f, c1 = 0.f, c2 = 0.f, c3 = 0.f;
        #pragma unroll 4
        for (int f = fh * 100; f < fh * 100 + 100; ++f) {
            float w = fc2_w[f * NCLS + o];
            c0 += s_h3[0][f] * w; c1 += s_h3[1][f] * w; c2 += s_h3[2][f] * w; c3 += s_h3[3][f] * w;
        }
        ps2[fh][0][o] = c0; ps2[fh][1][o] = c1; ps2[fh][2][o] = c2; ps2[fh][3][o] = c3;
    }
    __syncthreads();
    if (t < 160) {
        const int nd = t / 40, o = t % 40;
        out[(size_t)(n0 + nd) * NCLS + o] = ps2[0][nd][o] + ps2[1][nd][o] + fc2_b[o];
    }
}

extern "C" void kernel_launch(void* const* d_in, const int* in_sizes, int n_in,
                              void* d_out, int out_size, void* d_ws, size_t ws_size,
                              hipStream_t stream) {
    const void* x     = d_in[0];
    const void* adj   = d_in[1];
    const void* W_h   = d_in[2];
    const void* a_h   = d_in[3];
    const void* W_o   = d_in[4];
    const void* a_o   = d_in[5];
    const void* fc1_w = d_in[6];
    const void* fc1_b = d_in[7];
    const void* fc2_w = d_in[8];
    const void* fc2_b = d_in[9];
    float* out = (float*)d_out;

    char* ws = (char*)d_ws;                         // all offsets 16B-aligned
    int*   nbr   = (int*)(ws + 0);                  //  2,560,000 B
    int*   deg   = (int*)(ws + 2560000);            //     20,000 B
    float* Wh    = (float*)(ws + 2580000);          // 10,240,000 B
    float* f1    = (float*)(ws + 12820000);         //    160,000 B
    float* f2    = (float*)(ws + 12980000);         //    160,000 B
    float* h1    = (float*)(ws + 13140000);         // 10,240,000 B
    float* Wh2   = (float*)(ws + 23380000);         //  1,280,000 B
    float* g1    = (float*)(ws + 24660000);         //     20,000 B
    float* g2    = (float*)(ws + 24680000);         //     20,000 B
    u16*   xc    = (u16*)(ws + 24700000);           //  5,120,000 B
    u16*   whc   = (u16*)(ws + 29820000);           //    524,288 B
    float* a_hc  = (float*)(ws + 30344288);         //      4,096 B
    float* W_oc  = (float*)(ws + 30348384);         //    131,072 B
    float* a_oc  = (float*)(ws + 30479456);         //        512 B
    float* f1wc  = (float*)(ws + 30479968);         //     51,200 B
    float* f1bc  = (float*)(ws + 30531168);         //        800 B
    float* f2wc  = (float*)(ws + 30531968);         //     32,000 B
    float* f2bc  = (float*)(ws + 30563968);         //        160 B  (total ~30.6 MB)

    prep<<<NN + CVT_AB_BLKS + 8, 256, 0, stream>>>(x, W_h, adj, a_h, W_o, a_o,
                                                   fc1_w, fc1_b, fc2_w, fc2_b,
                                                   xc, whc, a_hc, W_oc, a_oc,
                                                   f1wc, f1bc, f2wc, f2bc, nbr, deg);
    gemm1_f<<<dim3(79, HEADS), 256, 0, stream>>>((const bf16_t*)xc, (const bf16_t*)whc,
                                                 a_hc, Wh, f1, f2);
    agg1<<<HEADS * NN / 4, 256, 0, stream>>>(Wh, f1, f2, nbr, deg, h1);
    gemm2_4<<<NN / 4, 256, 0, stream>>>(h1, W_oc, a_oc, Wh2, g1, g2);
    agg2_mlp<<<NN / 4, 256, 0, stream>>>(Wh2, g1, g2, nbr, deg,
                                         f1wc, f1bc, f2wc, f2bc, out);
}